// Round 1
// baseline (455.457 us; speedup 1.0000x reference)
//
#include <hip/hip_runtime.h>
#include <hip/hip_bf16.h>

typedef unsigned short u16;
typedef __attribute__((ext_vector_type(8))) __bf16 bf16x8;
typedef __attribute__((ext_vector_type(4))) float f32x4;
typedef __attribute__((ext_vector_type(8))) unsigned short ushort8;

// Shapes (fixed by reference setup_inputs): B=4,S=2048 -> M=8192; D_IN=D_OUT=4096; R=8
#define GM 8192
#define GN 4096
#define GK 4096

__device__ __forceinline__ u16 f2bf(float f) {
  // round-to-nearest-even f32 -> bf16 (finite inputs)
  unsigned u = __float_as_uint(f);
  u += 0x7fffu + ((u >> 16) & 1u);
  return (u16)(u >> 16);
}

// ---- kernel 1: W_eff = bf16(W + 2 * (B @ A))   [4096][4096]
__global__ void build_weff(const float* __restrict__ W,
                           const float* __restrict__ lA,
                           const float* __restrict__ lB,
                           u16* __restrict__ Weff) {
  const int o = blockIdx.x;  // output row (D_OUT)
  float b[8];
#pragma unroll
  for (int r = 0; r < 8; ++r) b[r] = 2.0f * lB[o * 8 + r];  // fold SCALE=2
  const float* wrow = W + (size_t)o * GK;
  u16* orow = Weff + (size_t)o * GK;
  for (int d = threadIdx.x * 4; d < GK; d += blockDim.x * 4) {
    float4 w = *reinterpret_cast<const float4*>(wrow + d);
    float a0 = w.x, a1 = w.y, a2 = w.z, a3 = w.w;
#pragma unroll
    for (int r = 0; r < 8; ++r) {
      float4 a = *reinterpret_cast<const float4*>(lA + r * GK + d);
      a0 += b[r] * a.x;
      a1 += b[r] * a.y;
      a2 += b[r] * a.z;
      a3 += b[r] * a.w;
    }
    ushort4 p;
    p.x = f2bf(a0);
    p.y = f2bf(a1);
    p.z = f2bf(a2);
    p.w = f2bf(a3);
    *reinterpret_cast<ushort4*>(orow + d) = p;
  }
}

// ---- kernel 2: x f32 -> bf16 (8 elems/thread, vectorized)
__global__ void cvt_bf16(const float* __restrict__ x, u16* __restrict__ xb) {
  const size_t i = ((size_t)blockIdx.x * blockDim.x + threadIdx.x) * 8;
  float4 v0 = *reinterpret_cast<const float4*>(x + i);
  float4 v1 = *reinterpret_cast<const float4*>(x + i + 4);
  ushort8 o;
  o[0] = f2bf(v0.x); o[1] = f2bf(v0.y); o[2] = f2bf(v0.z); o[3] = f2bf(v0.w);
  o[4] = f2bf(v1.x); o[5] = f2bf(v1.y); o[6] = f2bf(v1.z); o[7] = f2bf(v1.w);
  *reinterpret_cast<ushort8*>(xb + i) = o;
}

// ---- kernel 3: C[m][n] = sum_k A[m][k] * B[n][k]  (both operands K-major bf16, fp32 out)
// m97 structure: 128x128 tile, BK=64, 4 waves (2x2), 16x16x32 bf16 MFMA,
// global_load_lds width=16 staging, 2-barrier K-loop.
__device__ __forceinline__ void gload16(const void* g, void* l) {
  __builtin_amdgcn_global_load_lds(
      (const __attribute__((address_space(1))) void*)g,
      (__attribute__((address_space(3))) void*)l, 16, 0, 0);
}

__global__ __launch_bounds__(256) void gemm_bt(const u16* __restrict__ Ab,
                                               const u16* __restrict__ Bb,
                                               float* __restrict__ C) {
  constexpr int K = GK, N = GN;
  __shared__ u16 As[128 * 64];  // [row][k] linear, 16 KiB
  __shared__ u16 Bs[128 * 64];

  const int tid = threadIdx.x;
  const int wave = tid >> 6;
  const int lane = tid & 63;

  // XCD-aware swizzle: nwg = 2048, divisible by 8 -> simple bijective form
  const int nwg = gridDim.x;
  const int cpx = nwg >> 3;
  const int wg = ((int)blockIdx.x & 7) * cpx + ((int)blockIdx.x >> 3);
  const int nbx = N / 128;          // 32
  const int tm = wg / nbx;          // 0..63
  const int tn = wg % nbx;          // 0..31

  // staging: 256 threads x 16B = 4 KiB/round, 4 rounds per 16 KiB tile.
  // LDS dst is wave-uniform (base + lane*16 by HW); global src per-lane.
  const int r0 = tid >> 3;          // 0..31 (row within round)
  const int c0 = (tid & 7) * 8;     // k-elem offset (8 bf16 = 16B)
  const u16* aSrc = Ab + (size_t)(tm * 128 + r0) * K + c0;
  const u16* bSrc = Bb + (size_t)(tn * 128 + r0) * K + c0;

  // fragment addressing (verified layouts: A/B lane l holds 8 contiguous k at
  // row/col = l&15, k0 = 8*(l>>4); C/D: col = l&15, row = 4*(l>>4)+reg)
  const int wr = wave >> 1, wc = wave & 1;  // 2x2 wave grid, 64x64 each
  const int fr = lane & 15;
  const int fk = (lane >> 4) * 8;
  const u16* aF = &As[(wr * 64 + fr) * 64 + fk];
  const u16* bF = &Bs[(wc * 64 + fr) * 64 + fk];

  f32x4 acc[4][4] = {};

  for (int k0 = 0; k0 < K; k0 += 64) {
#pragma unroll
    for (int j = 0; j < 4; ++j) {
      gload16(aSrc + (size_t)(j * 32) * K + k0, &As[j * 2048 + wave * 512]);
      gload16(bSrc + (size_t)(j * 32) * K + k0, &Bs[j * 2048 + wave * 512]);
    }
    __syncthreads();  // compiler emits vmcnt(0) drain before barrier
#pragma unroll
    for (int kk = 0; kk < 64; kk += 32) {
      bf16x8 av[4], bv[4];
#pragma unroll
      for (int m = 0; m < 4; ++m)
        av[m] = *reinterpret_cast<const bf16x8*>(aF + m * 16 * 64 + kk);
#pragma unroll
      for (int n = 0; n < 4; ++n)
        bv[n] = *reinterpret_cast<const bf16x8*>(bF + n * 16 * 64 + kk);
#pragma unroll
      for (int m = 0; m < 4; ++m)
#pragma unroll
        for (int n = 0; n < 4; ++n)
          acc[m][n] = __builtin_amdgcn_mfma_f32_16x16x32_bf16(av[m], bv[n],
                                                              acc[m][n], 0, 0, 0);
    }
    __syncthreads();
  }

  // epilogue: C/D mapping col=lane&15, row=4*(lane>>4)+j (m89/m91-verified)
  const int orow = tm * 128 + wr * 64;
  const int ocol = tn * 128 + wc * 64;
  const int cr = (lane >> 4) * 4;
#pragma unroll
  for (int m = 0; m < 4; ++m)
#pragma unroll
    for (int n = 0; n < 4; ++n) {
      float* cp = C + (size_t)(orow + m * 16 + cr) * N + (ocol + n * 16 + fr);
#pragma unroll
      for (int j = 0; j < 4; ++j) cp[(size_t)j * N] = acc[m][n][j];
    }
}

extern "C" void kernel_launch(void* const* d_in, const int* in_sizes, int n_in,
                              void* d_out, int out_size, void* d_ws, size_t ws_size,
                              hipStream_t stream) {
  const float* x  = (const float*)d_in[0];   // [4,2048,4096] -> [8192][4096]
  const float* W  = (const float*)d_in[1];   // [4096][4096]
  const float* lA = (const float*)d_in[2];   // [8][4096]
  const float* lB = (const float*)d_in[3];   // [4096][8]
  float* out = (float*)d_out;                // [8192][4096]

  // workspace: W_eff bf16 (32 MiB) then x bf16 (64 MiB) = 96 MiB total
  u16* weff = (u16*)d_ws;
  u16* xb   = (u16*)((char*)d_ws + (size_t)GN * GK * sizeof(u16));

  build_weff<<<GN, 256, 0, stream>>>(W, lA, lB, weff);
  cvt_bf16<<<(size_t)GM * GK / (256 * 8), 256, 0, stream>>>(x, xb);
  gemm_bt<<<(GM / 128) * (GN / 128), 256, 0, stream>>>(xb, weff, out);
}

// Round 2
// 329.216 us; speedup vs baseline: 1.3835x; 1.3835x over previous
//
#include <hip/hip_runtime.h>
#include <hip/hip_bf16.h>

typedef unsigned short u16;
typedef __attribute__((ext_vector_type(8))) __bf16 bf16x8;
typedef __attribute__((ext_vector_type(4))) float f32x4;
typedef __attribute__((ext_vector_type(8))) unsigned short ushort8;

#define GM 8192
#define GN 4096
#define GK 4096
#define NT (GK / 64)  // 64 K-tiles of BK=64

__device__ __forceinline__ u16 f2bf(float f) {
  unsigned u = __float_as_uint(f);
  u += 0x7fffu + ((u >> 16) & 1u);
  return (u16)(u >> 16);
}

// ---- kernel 1: W_eff = bf16(W + 2 * (B @ A))   [4096][4096]
__global__ void build_weff(const float* __restrict__ W,
                           const float* __restrict__ lA,
                           const float* __restrict__ lB,
                           u16* __restrict__ Weff) {
  const int o = blockIdx.x;
  float b[8];
#pragma unroll
  for (int r = 0; r < 8; ++r) b[r] = 2.0f * lB[o * 8 + r];
  const float* wrow = W + (size_t)o * GK;
  u16* orow = Weff + (size_t)o * GK;
  for (int d = threadIdx.x * 4; d < GK; d += blockDim.x * 4) {
    float4 w = *reinterpret_cast<const float4*>(wrow + d);
    float a0 = w.x, a1 = w.y, a2 = w.z, a3 = w.w;
#pragma unroll
    for (int r = 0; r < 8; ++r) {
      float4 a = *reinterpret_cast<const float4*>(lA + r * GK + d);
      a0 += b[r] * a.x; a1 += b[r] * a.y; a2 += b[r] * a.z; a3 += b[r] * a.w;
    }
    ushort4 p;
    p.x = f2bf(a0); p.y = f2bf(a1); p.z = f2bf(a2); p.w = f2bf(a3);
    *reinterpret_cast<ushort4*>(orow + d) = p;
  }
}

// ---- kernel 2: x f32 -> bf16
__global__ void cvt_bf16(const float* __restrict__ x, u16* __restrict__ xb) {
  const size_t i = ((size_t)blockIdx.x * blockDim.x + threadIdx.x) * 8;
  float4 v0 = *reinterpret_cast<const float4*>(x + i);
  float4 v1 = *reinterpret_cast<const float4*>(x + i + 4);
  ushort8 o;
  o[0] = f2bf(v0.x); o[1] = f2bf(v0.y); o[2] = f2bf(v0.z); o[3] = f2bf(v0.w);
  o[4] = f2bf(v1.x); o[5] = f2bf(v1.y); o[6] = f2bf(v1.z); o[7] = f2bf(v1.w);
  *reinterpret_cast<ushort8*>(xb + i) = o;
}

// ---- kernel 3: 256x256-tile 8-phase GEMM, C[m][n] = sum_k A[m][k]*B[n][k]
// m201 template: BK=64, 8 waves (2Mx4N), 128 KiB LDS dbuf, st_16x32 swizzle,
// counted vmcnt(4) at tile boundaries, raw s_barrier, setprio around MFMA.
__device__ __forceinline__ void gload16(const u16* g, u16* l) {
  __builtin_amdgcn_global_load_lds(
      (const __attribute__((address_space(1))) void*)g,
      (__attribute__((address_space(3))) void*)l, 16, 0, 0);
}

#define BAR()                                  \
  do {                                         \
    asm volatile("" ::: "memory");             \
    __builtin_amdgcn_s_barrier();              \
    asm volatile("" ::: "memory");             \
  } while (0)

__global__ __launch_bounds__(512, 2) void gemm256(const u16* __restrict__ Ab,
                                                  const u16* __restrict__ Bb,
                                                  float* __restrict__ C) {
  // [buf][0=A,1=B][row*64 + k], 2*2*16384*2B = 128 KiB
  __shared__ u16 lds[2][2][256 * 64];

  const int tid = threadIdx.x;
  const int wv = tid >> 6;
  const int l = tid & 63;

  // XCD-aware swizzle: 512 blocks, 512 % 8 == 0 -> simple bijective form
  const int nwg = gridDim.x;
  const int cpx = nwg >> 3;
  const int wg = ((int)blockIdx.x & 7) * cpx + ((int)blockIdx.x >> 3);
  const int tm = wg >> 4;   // GN/256 = 16 tiles in N
  const int tn = wg & 15;

  const int wr = wv >> 2;   // 0..1  (M split)
  const int wc = wv & 3;    // 0..3  (N split)

  // --- staging constants (inverse-swizzled global source, linear LDS dest) ---
  // LDS linear byte o = j*8192 + wv*1024 + l*16; logical = o ^ ((o>>9)&1)<<5
  // -> row = j*64 + wv*8 + (l>>3); kelem = (l&7)*8 ^ (l>=32 ? 16 : 0)
  const int srow = (wv << 3) + (l >> 3);
  const int skel = ((l & 7) << 3) ^ ((l & 32) ? 16 : 0);
  const u16* aG = Ab + (size_t)(tm * 256) * GK;
  const u16* bG = Bb + (size_t)(tn * 256) * GK;

  // --- reader constants: frag (row = base + m*16 + (l&15), k = 8*(l>>4)+kk) ---
  // swizzle on read: kelem ^= (row&4) ? 16 : 0  (row&4 invariant under m*16)
  const int frow = l & 15;
  const int fksw = ((l >> 4) << 3) ^ ((frow & 4) ? 16 : 0);
  const int arow = wr * 128 + frow;
  const int brow = wc * 64 + frow;

  // stage half-tile: th = K-tile, r: 0=A0,1=A1,2=B0,3=B1  (2 x gload16/wave)
  auto STAGE = [&](int th, int r) {
    const int k0 = th << 6;
    const u16* src = (r < 2 ? aG : bG) +
                     (size_t)((r & 1) * 128 + srow) * GK + k0 + skel;
    u16* dst = &lds[th & 1][r >> 1][(r & 1) * 8192 + wv * 512];
#pragma unroll
    for (int j = 0; j < 2; ++j)
      gload16(src + (size_t)(j * 64) * GK, dst + j * 4096);
  };

  // prologue: tile0 (A0,A1,B0,B1) + tile1 (A0,A1) = 6 half-tiles, 12 loads/wave
  STAGE(0, 0); STAGE(0, 1); STAGE(0, 2); STAGE(0, 3);
  STAGE(1, 0); STAGE(1, 1);

  f32x4 acc[8][4] = {};
  bf16x8 af[8][2], bfr[4][2];

  asm volatile("s_waitcnt vmcnt(4)" ::: "memory");  // tile0 landed
  BAR();

  for (int t = 0; t < NT; ++t) {
    const u16* A = &lds[t & 1][0][0];
    const u16* B = &lds[t & 1][1][0];
#pragma unroll
    for (int q = 0; q < 4; ++q) {
      // --- register subtile loads (ds_read_b128) ---
      if (q == 0) {
#pragma unroll
        for (int n = 0; n < 4; ++n)
#pragma unroll
          for (int s = 0; s < 2; ++s)
            bfr[n][s] = *reinterpret_cast<const bf16x8*>(
                B + (brow + n * 16) * 64 + fksw + s * 32);
#pragma unroll
        for (int m = 0; m < 2; ++m)
#pragma unroll
          for (int s = 0; s < 2; ++s)
            af[m][s] = *reinterpret_cast<const bf16x8*>(
                A + (arow + m * 16) * 64 + fksw + s * 32);
      } else if (q == 1) {
        // all remaining A frags must be in regs before q2 stages tile t+2 A0
#pragma unroll
        for (int m = 2; m < 8; ++m)
#pragma unroll
          for (int s = 0; s < 2; ++s)
            af[m][s] = *reinterpret_cast<const bf16x8*>(
                A + (arow + m * 16) * 64 + fksw + s * 32);
      }
      // --- stage one half-tile (ledger: B(t+1)->other buf at q0/q1;
      //     A(t+2)->this buf at q2/q3, legal: A fully reg-resident after q1) ---
      if (q == 0) { if (t + 1 < NT) STAGE(t + 1, 2); }
      else if (q == 1) { if (t + 1 < NT) STAGE(t + 1, 3); }
      else if (q == 2) { if (t + 2 < NT) STAGE(t + 2, 0); }
      else { if (t + 2 < NT) STAGE(t + 2, 1); }

      BAR();
      __builtin_amdgcn_s_setprio(1);
#pragma unroll
      for (int mm = 0; mm < 2; ++mm) {
#pragma unroll
        for (int n = 0; n < 4; ++n)
#pragma unroll
          for (int s = 0; s < 2; ++s)
            acc[2 * q + mm][n] = __builtin_amdgcn_mfma_f32_16x16x32_bf16(
                af[2 * q + mm][s], bfr[n][s], acc[2 * q + mm][n], 0, 0, 0);
      }
      __builtin_amdgcn_s_setprio(0);
      // counted vmcnt once per K-tile (phase 4): tile t+1 fully landed,
      // 2 half-tiles (A of t+2) left in flight. Drain only before last tile.
      if (q == 3) {
        if (t == NT - 2)
          asm volatile("s_waitcnt vmcnt(0)" ::: "memory");
        else if (t < NT - 2)
          asm volatile("s_waitcnt vmcnt(4)" ::: "memory");
      }
      BAR();
    }
  }

  // epilogue: C/D layout col = l&15, row = 4*(l>>4)+j
  const int orow = tm * 256 + wr * 128 + ((l >> 4) << 2);
  const int ocol = tn * 256 + wc * 64 + (l & 15);
#pragma unroll
  for (int m = 0; m < 8; ++m)
#pragma unroll
    for (int n = 0; n < 4; ++n) {
      float* cp = C + (size_t)(orow + m * 16) * GN + (ocol + n * 16);
#pragma unroll
      for (int j = 0; j < 4; ++j) cp[(size_t)j * GN] = acc[m][n][j];
    }
}

extern "C" void kernel_launch(void* const* d_in, const int* in_sizes, int n_in,
                              void* d_out, int out_size, void* d_ws, size_t ws_size,
                              hipStream_t stream) {
  const float* x  = (const float*)d_in[0];
  const float* W  = (const float*)d_in[1];
  const float* lA = (const float*)d_in[2];
  const float* lB = (const float*)d_in[3];
  float* out = (float*)d_out;

  u16* weff = (u16*)d_ws;
  u16* xb = (u16*)((char*)d_ws + (size_t)GN * GK * sizeof(u16));

  build_weff<<<GN, 256, 0, stream>>>(W, lA, lB, weff);
  cvt_bf16<<<(size_t)GM * GK / (256 * 8), 256, 0, stream>>>(x, xb);
  gemm256<<<(GM / 256) * (GN / 256), 512, 0, stream>>>(xb, weff, out);
}

// Round 3
// 308.097 us; speedup vs baseline: 1.4783x; 1.0685x over previous
//
#include <hip/hip_runtime.h>
#include <hip/hip_bf16.h>

typedef unsigned short u16;
typedef __attribute__((ext_vector_type(8))) __bf16 bf16x8;
typedef __attribute__((ext_vector_type(4))) float f32x4;
typedef __attribute__((ext_vector_type(8))) unsigned short ushort8;

#define GM 8192
#define GN 4096
#define GK 4096
#define NT (GK / 64)  // 64 K-tiles of BK=64

__device__ __forceinline__ u16 f2bf(float f) {
  unsigned u = __float_as_uint(f);
  u += 0x7fffu + ((u >> 16) & 1u);
  return (u16)(u >> 16);
}

// ---- kernel 1: W_eff = bf16(W + 2 * (B @ A))   [4096][4096]
__global__ void build_weff(const float* __restrict__ W,
                           const float* __restrict__ lA,
                           const float* __restrict__ lB,
                           u16* __restrict__ Weff) {
  const int o = blockIdx.x;
  float b[8];
#pragma unroll
  for (int r = 0; r < 8; ++r) b[r] = 2.0f * lB[o * 8 + r];
  const float* wrow = W + (size_t)o * GK;
  u16* orow = Weff + (size_t)o * GK;
  for (int d = threadIdx.x * 4; d < GK; d += blockDim.x * 4) {
    float4 w = *reinterpret_cast<const float4*>(wrow + d);
    float a0 = w.x, a1 = w.y, a2 = w.z, a3 = w.w;
#pragma unroll
    for (int r = 0; r < 8; ++r) {
      float4 a = *reinterpret_cast<const float4*>(lA + r * GK + d);
      a0 += b[r] * a.x; a1 += b[r] * a.y; a2 += b[r] * a.z; a3 += b[r] * a.w;
    }
    ushort4 p;
    p.x = f2bf(a0); p.y = f2bf(a1); p.z = f2bf(a2); p.w = f2bf(a3);
    *reinterpret_cast<ushort4*>(orow + d) = p;
  }
}

// ---- kernel 2: x f32 -> bf16
__global__ void cvt_bf16(const float* __restrict__ x, u16* __restrict__ xb) {
  const size_t i = ((size_t)blockIdx.x * blockDim.x + threadIdx.x) * 8;
  float4 v0 = *reinterpret_cast<const float4*>(x + i);
  float4 v1 = *reinterpret_cast<const float4*>(x + i + 4);
  ushort8 o;
  o[0] = f2bf(v0.x); o[1] = f2bf(v0.y); o[2] = f2bf(v0.z); o[3] = f2bf(v0.w);
  o[4] = f2bf(v1.x); o[5] = f2bf(v1.y); o[6] = f2bf(v1.z); o[7] = f2bf(v1.w);
  *reinterpret_cast<ushort8*>(xb + i) = o;
}

// ---- kernel 3: 256x256-tile 8-phase GEMM, C[m][n] = sum_k A[m][k]*B[n][k]
// 3-bit LDS swizzle: logical (row,k) stored at elem row*64 + (k ^ swz(row)),
// swz(row) = (row & 0xE) << 2  (row bits 1..3 -> kelem bits 3..5).
// Spreads the 16 rows of a 16-lane ds_read_b128 group across 8 16B bank
// slots (2 lanes/slot = free). Staging source pre-applies the same XOR
// (gload_lds LDS dest stays linear; XOR bijective within each row).
__device__ __forceinline__ void gload16(const u16* g, u16* l) {
  __builtin_amdgcn_global_load_lds(
      (const __attribute__((address_space(1))) void*)g,
      (__attribute__((address_space(3))) void*)l, 16, 0, 0);
}

#define BAR()                                  \
  do {                                         \
    asm volatile("" ::: "memory");             \
    __builtin_amdgcn_s_barrier();              \
    asm volatile("" ::: "memory");             \
  } while (0)

__global__ __launch_bounds__(512, 2) void gemm256(const u16* __restrict__ Ab,
                                                  const u16* __restrict__ Bb,
                                                  float* __restrict__ C) {
  // [buf][0=A,1=B][row*64 + k], 2*2*16384*2B = 128 KiB
  __shared__ u16 lds[2][2][256 * 64];

  const int tid = threadIdx.x;
  const int wv = tid >> 6;
  const int l = tid & 63;

  // XCD-aware swizzle: 512 blocks, 512 % 8 == 0 -> simple bijective form
  const int nwg = gridDim.x;
  const int cpx = nwg >> 3;
  const int wg = ((int)blockIdx.x & 7) * cpx + ((int)blockIdx.x >> 3);
  const int tm = wg >> 4;   // GN/256 = 16 tiles in N
  const int tn = wg & 15;

  const int wr = wv >> 2;   // 0..1  (M split)
  const int wc = wv & 3;    // 0..3  (N split)

  // --- staging constants ---
  // linear LDS elem e = (r&1)*8192 + j*4096 + wv*512 + l*8
  // row = e/64 : bits0-2 = l>>3, bit3 = wv&1 ; kelem_lds = (l&7)*8
  // logical k = kelem_lds ^ swz(row)
  const int srow = (wv << 3) + (l >> 3);
  const int srl = ((wv & 1) << 3) | (l >> 3);          // row bits 0..3
  const int skel = ((l & 7) << 3) ^ ((srl & 0xE) << 2);
  const u16* aG = Ab + (size_t)(tm * 256) * GK;
  const u16* bG = Bb + (size_t)(tn * 256) * GK;

  // --- reader constants: frag row = base + m*16 + (l&15), k = 8*(l>>4) + s*32
  // LDS kelem = k ^ swz(row); row bits 1..3 come from l&15 only.
  const int frow = l & 15;
  const int fksw = ((l >> 4) << 3) ^ ((frow & 0xE) << 2);
  const int arow = wr * 128 + frow;
  const int brow = wc * 64 + frow;

  // stage half-tile: th = K-tile, r: 0=A0,1=A1,2=B0,3=B1  (2 x gload16/wave)
  auto STAGE = [&](int th, int r) {
    const int k0 = th << 6;
    const u16* src = (r < 2 ? aG : bG) +
                     (size_t)((r & 1) * 128 + srow) * GK + k0 + skel;
    u16* dst = &lds[th & 1][r >> 1][(r & 1) * 8192 + wv * 512];
#pragma unroll
    for (int j = 0; j < 2; ++j)
      gload16(src + (size_t)(j * 64) * GK, dst + j * 4096);
  };

  // prologue: tile0 (A0,A1,B0,B1) + tile1 (A0,A1) = 6 half-tiles
  STAGE(0, 0); STAGE(0, 1); STAGE(0, 2); STAGE(0, 3);
  STAGE(1, 0); STAGE(1, 1);

  f32x4 acc[8][4] = {};
  bf16x8 af[8][2], bfr[4][2];

  asm volatile("s_waitcnt vmcnt(4)" ::: "memory");  // tile0 landed
  BAR();

  for (int t = 0; t < NT; ++t) {
    const u16* A = &lds[t & 1][0][0];
    const u16* B = &lds[t & 1][1][0];
#pragma unroll
    for (int q = 0; q < 4; ++q) {
      // --- register subtile loads (ds_read_b128) ---
      if (q == 0) {
#pragma unroll
        for (int n = 0; n < 4; ++n)
#pragma unroll
          for (int s = 0; s < 2; ++s)
            bfr[n][s] = *reinterpret_cast<const bf16x8*>(
                B + (brow + n * 16) * 64 + (fksw ^ (s << 5)));
#pragma unroll
        for (int m = 0; m < 2; ++m)
#pragma unroll
          for (int s = 0; s < 2; ++s)
            af[m][s] = *reinterpret_cast<const bf16x8*>(
                A + (arow + m * 16) * 64 + (fksw ^ (s << 5)));
      } else if (q == 1) {
        // all remaining A frags must be in regs before q2 stages tile t+2 A0
#pragma unroll
        for (int m = 2; m < 8; ++m)
#pragma unroll
          for (int s = 0; s < 2; ++s)
            af[m][s] = *reinterpret_cast<const bf16x8*>(
                A + (arow + m * 16) * 64 + (fksw ^ (s << 5)));
      }
      // --- stage one half-tile (B(t+1)->other buf at q0/q1;
      //     A(t+2)->this buf at q2/q3, legal: A reg-resident after q1) ---
      if (q == 0) { if (t + 1 < NT) STAGE(t + 1, 2); }
      else if (q == 1) { if (t + 1 < NT) STAGE(t + 1, 3); }
      else if (q == 2) { if (t + 2 < NT) STAGE(t + 2, 0); }
      else { if (t + 2 < NT) STAGE(t + 2, 1); }

      BAR();
      __builtin_amdgcn_s_setprio(1);
#pragma unroll
      for (int mm = 0; mm < 2; ++mm) {
#pragma unroll
        for (int n = 0; n < 4; ++n)
#pragma unroll
          for (int s = 0; s < 2; ++s)
            acc[2 * q + mm][n] = __builtin_amdgcn_mfma_f32_16x16x32_bf16(
                af[2 * q + mm][s], bfr[n][s], acc[2 * q + mm][n], 0, 0, 0);
      }
      __builtin_amdgcn_s_setprio(0);
      // counted vmcnt once per K-tile (phase 4); drain only before last tile.
      if (q == 3) {
        if (t == NT - 2)
          asm volatile("s_waitcnt vmcnt(0)" ::: "memory");
        else if (t < NT - 2)
          asm volatile("s_waitcnt vmcnt(4)" ::: "memory");
      }
      BAR();
    }
  }

  // epilogue: C/D layout col = l&15, row = 4*(l>>4)+j
  const int orow = tm * 256 + wr * 128 + ((l >> 4) << 2);
  const int ocol = tn * 256 + wc * 64 + (l & 15);
#pragma unroll
  for (int m = 0; m < 8; ++m)
#pragma unroll
    for (int n = 0; n < 4; ++n) {
      float* cp = C + (size_t)(orow + m * 16) * GN + (ocol + n * 16);
#pragma unroll
      for (int j = 0; j < 4; ++j) cp[(size_t)j * GN] = acc[m][n][j];
    }
}

extern "C" void kernel_launch(void* const* d_in, const int* in_sizes, int n_in,
                              void* d_out, int out_size, void* d_ws, size_t ws_size,
                              hipStream_t stream) {
  const float* x  = (const float*)d_in[0];
  const float* W  = (const float*)d_in[1];
  const float* lA = (const float*)d_in[2];
  const float* lB = (const float*)d_in[3];
  float* out = (float*)d_out;

  u16* weff = (u16*)d_ws;
  u16* xb = (u16*)((char*)d_ws + (size_t)GN * GK * sizeof(u16));

  build_weff<<<GN, 256, 0, stream>>>(W, lA, lB, weff);
  cvt_bf16<<<(size_t)GM * GK / (256 * 8), 256, 0, stream>>>(x, xb);
  gemm256<<<(GM / 256) * (GN / 256), 512, 0, stream>>>(xb, weff, out);
}